// Round 3
// baseline (92.880 us; speedup 1.0000x reference)
//
#include <hip/hip_runtime.h>
#include <math.h>

// B=64, IN=1024, output_size=1024, D_MODEL=64, X_KS=Y_KS=32, HIDDEN=256
constexpr int B    = 64;
constexpr int IN   = 1024;
constexpr int OUTN = 1024;
constexpr int H    = 256;

#define LN10000 9.210340371976184f
#define TWO_LOG2E 2.8853900817779268f   // 2*log2(e); exp(2x) = exp2(x*TWO_LOG2E)

__device__ __forceinline__ float fast_tanh(float x) {
    // tanh(x) = 1 - 2/(e^{2x}+1); error budget is huge (absmax thresh 1.47)
    x = fminf(fmaxf(x, -15.0f), 15.0f);
    float e = __builtin_amdgcn_exp2f(x * TWO_LOG2E);
    return 1.0f - 2.0f * __builtin_amdgcn_rcpf(e + 1.0f);
}

// ---------------------------------------------------------------------------
// K0: 64 blocks = (table in [0,2), p in [0,32)), 256 threads = c.
//   PA[p][c] = b1[c] + sum_d pe(p)[d] * W1[d][c]       (pe_x rows 0..63)
//   PY[p][c] =         sum_d pe(p)[d] * W1[64+d][c]    (pe_y rows 64..127)
// (HPE now folded into k2 — it only needs one og row per block.)
// ---------------------------------------------------------------------------
__global__ void __launch_bounds__(256) k0_tables(const float* __restrict__ W1,
                                                 const float* __restrict__ b1,
                                                 float* __restrict__ PA,
                                                 float* __restrict__ PY) {
    __shared__ float pe[64];
    const int blk = blockIdx.x, tid = threadIdx.x;
    const int p = blk & 31, table = blk >> 5;
    if (tid < 32) {
        float freq = expf(-(2.0f * (float)tid / 64.0f) * LN10000);
        float a = (float)p * freq;
        pe[2 * tid]     = sinf(a);
        pe[2 * tid + 1] = cosf(a);
    }
    __syncthreads();
    const float* src = (table == 0) ? W1 : (W1 + 64 * H);
    float acc = (table == 0) ? b1[tid] : 0.0f;
    #pragma unroll 16
    for (int d = 0; d < 64; ++d) acc += pe[d] * src[d * H + tid];   // coalesced 1KB/row
    float* dst = (table == 0) ? PA : PY;
    dst[p * H + tid] = acc;
}

// ---------------------------------------------------------------------------
// K1: 256 blocks = (b, cq), 1024 threads (16 waves -> 4/SIMD).
// Register/shuffle version: lane L of wave jg holds xr = x[b][jg*64+L], so
// every x access in the Q-matmul AND the tanh core is a within-wave shuffle.
// W1 x-chunk column in 32 VGPRs (coalesced loads). PY: 2 scalar loads (a
// thread only ever uses its own 2 jy rows). Only LDS left: As (cl<->jx remap,
// 2 writes + 32 2-way-free reads per thread) and the 2 reductions.
// ---------------------------------------------------------------------------
__global__ void __launch_bounds__(1024, 4) k1_v(const float* __restrict__ x,
                                                const float* __restrict__ W1,
                                                const float* __restrict__ PA,
                                                const float* __restrict__ PY,
                                                float* __restrict__ v,
                                                float* __restrict__ S) {
    __shared__ float As[2048];       // As[jx][cl] = b1 + pe_x@W1 + Q  (per c-slice)
    __shared__ float red[1024];
    __shared__ float sred[16];
    const int blk = blockIdx.x, tid = threadIdx.x;
    const int b = blk >> 2, cq = blk & 3, c0 = cq * 64;
    const int cl = tid & 63, jg = tid >> 6;   // jg in [0,16)
    const int p0 = jg * 2;

    const float xr = x[b * IN + tid];         // wave jg, lane L: x[b][jg*64+L]
    float w1reg[32];
    #pragma unroll
    for (int k = 0; k < 32; ++k) w1reg[k] = W1[(128 + k) * H + c0 + cl];
    float acc0 = PA[p0 * H + c0 + cl];
    float acc1 = PA[(p0 + 1) * H + c0 + cl];
    const float py0 = PY[p0 * H + c0 + cl];
    const float py1 = PY[(p0 + 1) * H + c0 + cl];

    if (cq == 0) {                   // S[b] partial: butterfly within wave
        float s = xr;
        #pragma unroll
        for (int off = 32; off > 0; off >>= 1) s += __shfl_xor(s, off, 64);
        if (cl == 0) sred[jg] = s;
    }

    // Q: acc_r += sum_k x[b][(p0+r)*32+k] * W1[128+k][c]; x via shuffle
    #pragma unroll
    for (int k = 0; k < 32; ++k) acc0 += __shfl(xr, k, 64) * w1reg[k];
    #pragma unroll
    for (int k = 0; k < 32; ++k) acc1 += __shfl(xr, 32 + k, 64) * w1reg[k];

    As[p0 * 64 + cl]       = acc0;
    As[(p0 + 1) * 64 + cl] = acc1;
    __syncthreads();

    if (cq == 0 && tid == 0) {
        float s = 0.0f;
        #pragma unroll
        for (int g = 0; g < 16; ++g) s += sred[g];
        S[b] = s;
    }

    // core: acc = sum_jx As-load once, two tanh (jy = p0, p0+1), x via shuffle
    float acc = 0.0f;
    #pragma unroll
    for (int jx = 0; jx < 32; ++jx) {
        const float a = As[jx * 64 + cl];          // 2-way bank alias: free
        acc += __shfl(xr, jx, 64)      * fast_tanh(a + py0);
        acc += __shfl(xr, 32 + jx, 64) * fast_tanh(a + py1);
    }
    red[tid] = acc;                  // layout jg*64 + cl == tid
    __syncthreads();
    if (tid < 64) {
        float s = 0.0f;
        #pragma unroll
        for (int g = 0; g < 16; ++g) s += red[g * 64 + tid];
        v[b * H + c0 + tid] = s;
    }
}

// ---------------------------------------------------------------------------
// K2: 256 blocks = (og, bg), 1024 threads (16 waves -> 4/SIMD).
// h = tid>>8 in [0,4): 4-way c-split of phases 1/3. hpe generated in-block
// (trig in-lane + shfl broadcast, 4 waves). os read as float4 broadcasts.
// Wb2 read from global (32KB, L1-resident) — no LDS staging.
// ---------------------------------------------------------------------------
__global__ void __launch_bounds__(1024) k2_out(const float* __restrict__ v,
                                               const float* __restrict__ S,
                                               const float* __restrict__ W2,
                                               const float* __restrict__ b2,
                                               const float* __restrict__ Wb1,
                                               const float* __restrict__ bb1,
                                               const float* __restrict__ Wb2,
                                               const float* __restrict__ bb2,
                                               float* __restrict__ out) {
    __shared__ float vsh[2048];      // v rows for 8 samples
    __shared__ float hpe[256];       // bb1 + pe(og) @ Wb1[32:96]
    __shared__ float osp[1024];      // phase-1 partials (4 quarters)
    __shared__ float os[256];        // out-tile (pre-bias)
    __shared__ float hbs[2048];      // tanh activations
    __shared__ float bp[1024];       // phase-3 partials
    __shared__ float Ssh[8];
    const int blk = blockIdx.x, tid = threadIdx.x;
    const int og = blk & 31, bg = blk >> 5, b0 = bg * 8;
    const int h = tid >> 8, u = tid & 255, bl = u >> 5, ol = u & 31;

    ((float2*)vsh)[tid] = ((const float2*)(v + b0 * H))[tid];
    if (tid < 8) Ssh[tid] = S[b0 + tid];
    if (tid < 256) {                 // hpe by waves 0..3: thread owns c = tid
        const int L = tid & 63;
        float freq = expf(-(2.0f * (float)(L >> 1) / 64.0f) * LN10000);
        float a = (float)og * freq;
        float pel = (L & 1) ? cosf(a) : sinf(a);   // lane L holds pe(og)[L]
        float accp = bb1[tid];
        #pragma unroll 16
        for (int d = 0; d < 64; ++d)
            accp += __shfl(pel, d, 64) * Wb1[(32 + d) * H + tid];   // coalesced
        hpe[tid] = accp;
    }
    __syncthreads();

    const int o = og * 32 + ol;
    // phase 1: os[bl][ol] = S*b2 + v[b]·W2[:,o]  (c-quarter per h)
    {
        float acc = (h == 0) ? Ssh[bl] * b2[o] : 0.0f;
        const float4* vr = (const float4*)(vsh + bl * H + h * 64);
        #pragma unroll
        for (int c4 = 0; c4 < 16; ++c4) {
            float4 v4 = vr[c4];
            const int c = h * 64 + c4 * 4;
            acc += v4.x * W2[(c + 0) * OUTN + o];
            acc += v4.y * W2[(c + 1) * OUTN + o];
            acc += v4.z * W2[(c + 2) * OUTN + o];
            acc += v4.w * W2[(c + 3) * OUTN + o];
        }
        osp[h * 256 + u] = acc;
    }
    __syncthreads();
    if (tid < 256)
        os[tid] = osp[tid] + osp[256 + tid] + osp[512 + tid] + osp[768 + tid];
    __syncthreads();
    // phase 2: hb[bl][c] = tanh(hpe[c] + sum_k os[bl][k]*Wb1[k][c]),
    // thread covers c = h*64 + {0,32} + ol; os via float4 broadcasts
    {
        float a0 = hpe[h * 64 + ol];
        float a1 = hpe[h * 64 + 32 + ol];
        const float4* osr = (const float4*)(os + bl * 32);
        #pragma unroll
        for (int k4 = 0; k4 < 8; ++k4) {
            float4 o4 = osr[k4];
            const float* wr = Wb1 + (k4 * 4) * H + h * 64 + ol;
            a0 += o4.x * wr[0];         a1 += o4.x * wr[32];
            a0 += o4.y * wr[H];         a1 += o4.y * wr[H + 32];
            a0 += o4.z * wr[2 * H];     a1 += o4.z * wr[2 * H + 32];
            a0 += o4.w * wr[3 * H];     a1 += o4.w * wr[3 * H + 32];
        }
        hbs[bl * H + h * 64 + ol]      = fast_tanh(a0);
        hbs[bl * H + h * 64 + 32 + ol] = fast_tanh(a1);
    }
    __syncthreads();
    // phase 3: bias = bb2 + hb·Wb2  (c-quarter per h, Wb2 from global/L1)
    {
        float bias = (h == 0) ? bb2[ol] : 0.0f;
        const float4* hr = (const float4*)(hbs + bl * H + h * 64);
        #pragma unroll
        for (int c4 = 0; c4 < 16; ++c4) {
            float4 h4 = hr[c4];
            const int c = h * 64 + c4 * 4;
            bias += h4.x * Wb2[(c + 0) * 32 + ol];
            bias += h4.y * Wb2[(c + 1) * 32 + ol];
            bias += h4.z * Wb2[(c + 2) * 32 + ol];
            bias += h4.w * Wb2[(c + 3) * 32 + ol];
        }
        bp[h * 256 + u] = bias;
    }
    __syncthreads();
    if (tid < 256) {
        out[(b0 + (tid >> 5)) * OUTN + og * 32 + (tid & 31)] =
            os[tid] + bp[tid] + bp[256 + tid] + bp[512 + tid] + bp[768 + tid];
    }
}

// ---------------------------------------------------------------------------
extern "C" void kernel_launch(void* const* d_in, const int* in_sizes, int n_in,
                              void* d_out, int out_size, void* d_ws, size_t ws_size,
                              hipStream_t stream) {
    const float* x   = (const float*)d_in[0];
    // d_in[1] = output_size (fixed 1024)
    const float* W1  = (const float*)d_in[2];
    const float* b1  = (const float*)d_in[3];
    const float* W2  = (const float*)d_in[4];
    const float* b2  = (const float*)d_in[5];
    const float* Wb1 = (const float*)d_in[6];
    const float* bb1 = (const float*)d_in[7];
    const float* Wb2 = (const float*)d_in[8];
    const float* bb2 = (const float*)d_in[9];
    float* out = (float*)d_out;

    float* v  = (float*)d_ws;        // B*H
    float* S  = v + B * H;           // B
    float* PA = S + B;               // 32*H
    float* PY = PA + 32 * H;         // 32*H   (total 131 KB; ws is 256 MiB)

    hipLaunchKernelGGL(k0_tables, dim3(64),    dim3(256),  0, stream, W1, b1, PA, PY);
    hipLaunchKernelGGL(k1_v,      dim3(B * 4), dim3(1024), 0, stream, x, W1, PA, PY, v, S);
    hipLaunchKernelGGL(k2_out,    dim3(256),   dim3(1024), 0, stream,
                       v, S, W2, b2, Wb1, bb1, Wb2, bb2, out);
}